// Round 1
// baseline (146.246 us; speedup 1.0000x reference)
//
#include <hip/hip_runtime.h>
#include <hip/hip_fp16.h>

#define GAT_ALPHA 0.2f
#define GAT_NEG_INF -9.0e15f

typedef _Float16 half8_t __attribute__((ext_vector_type(8)));
typedef float f32x4 __attribute__((ext_vector_type(4)));

// k1: MFMA f16 GEMM. Wh16 = fp16(h @ W_j); e1 = h·vi + ab; e2 = h·vj,
// where vi = W_i@a_i, vj = W_j@a_j (both computed in the prologue: vi on
// threads 0..127, vj on threads 128..255 in parallel). e2 via h·vj is
// algebraically identical to (h@W_j)@a_j but skips the fp16 round-trip and
// deletes the acc-based epilogue reduction.
__global__ __launch_bounds__(256) void gat_transform_mfma(
    const float* __restrict__ h, const float* __restrict__ Wi,
    const float* __restrict__ Wj, const float* __restrict__ aw,
    const float* __restrict__ ab,
    __half* __restrict__ Wh16, float* __restrict__ e1, float* __restrict__ e2,
    int N) {
    __shared__ _Float16 sWt[128 * 136];  // W_j^T, padded: 34816 B
    __shared__ float svi[128];           // vi = W_i @ a_i
    __shared__ float svj[128];           // vj = W_j @ a_j
    const int t = threadIdx.x;

    // prologue 1: vi (t<128) and vj (t>=128) in parallel
    {
        const int r = t & 127;
        const float* wsrc = (t < 128) ? Wi : Wj;
        const float* asrc = aw + ((t < 128) ? 0 : 128);
        const float4* wrow = (const float4*)(wsrc + (size_t)r * 128);
        const float4* a4 = (const float4*)asrc;
        float s = 0.f;
        #pragma unroll
        for (int i = 0; i < 32; ++i) {
            float4 w = wrow[i], a = a4[i];
            s = fmaf(w.x, a.x, s); s = fmaf(w.y, a.y, s);
            s = fmaf(w.z, a.z, s); s = fmaf(w.w, a.w, s);
        }
        if (t < 128) svi[r] = s; else svj[r] = s;
    }
    // prologue 2: W_j^T into LDS as fp16
    for (int i = t; i < 128 * 128; i += 256) {
        int k = i >> 7, n = i & 127;          // W_j[k][n] row-major read
        sWt[n * 136 + k] = (_Float16)Wj[i];
    }
    __syncthreads();

    const int wave = t >> 6, lane = t & 63, q = lane >> 4, l16 = lane & 15;
    const float abv = ab[0];

    // vi/vj chunks this lane consumes: dims s*32 + q*8 + j
    float vir[4][8], vjr[4][8];
    #pragma unroll
    for (int s = 0; s < 4; ++s) {
        #pragma unroll
        for (int j = 0; j < 8; ++j) {
            vir[s][j] = svi[s * 32 + q * 8 + j];
            vjr[s][j] = svj[s * 32 + q * 8 + j];
        }
    }

    const int ntiles = (N + 15) >> 4;
    for (int tile = blockIdx.x * 4 + wave; tile < ntiles; tile += gridDim.x * 4) {
        const int base = tile << 4;
        int row = base + l16; if (row >= N) row = N - 1;  // clamp tail
        const float* hp = h + (size_t)row * 128 + q * 8;

        half8_t af[4];
        float pe1 = 0.f, pe2 = 0.f;  // fp32-exact partials of h·vi, h·vj
        #pragma unroll
        for (int s = 0; s < 4; ++s) {
            float4 f0 = *(const float4*)(hp + s * 32);
            float4 f1 = *(const float4*)(hp + s * 32 + 4);
            pe1 = fmaf(f0.x, vir[s][0], pe1); pe1 = fmaf(f0.y, vir[s][1], pe1);
            pe1 = fmaf(f0.z, vir[s][2], pe1); pe1 = fmaf(f0.w, vir[s][3], pe1);
            pe1 = fmaf(f1.x, vir[s][4], pe1); pe1 = fmaf(f1.y, vir[s][5], pe1);
            pe1 = fmaf(f1.z, vir[s][6], pe1); pe1 = fmaf(f1.w, vir[s][7], pe1);
            pe2 = fmaf(f0.x, vjr[s][0], pe2); pe2 = fmaf(f0.y, vjr[s][1], pe2);
            pe2 = fmaf(f0.z, vjr[s][2], pe2); pe2 = fmaf(f0.w, vjr[s][3], pe2);
            pe2 = fmaf(f1.x, vjr[s][4], pe2); pe2 = fmaf(f1.y, vjr[s][5], pe2);
            pe2 = fmaf(f1.z, vjr[s][6], pe2); pe2 = fmaf(f1.w, vjr[s][7], pe2);
            half8_t a;
            a[0] = (_Float16)f0.x; a[1] = (_Float16)f0.y;
            a[2] = (_Float16)f0.z; a[3] = (_Float16)f0.w;
            a[4] = (_Float16)f1.x; a[5] = (_Float16)f1.y;
            a[6] = (_Float16)f1.z; a[7] = (_Float16)f1.w;
            af[s] = a;
        }

        f32x4 acc[8];
        #pragma unroll
        for (int c = 0; c < 8; ++c) { f32x4 z = {0.f, 0.f, 0.f, 0.f}; acc[c] = z; }

        const _Float16* wbase = sWt + l16 * 136 + q * 8;
        #pragma unroll
        for (int s = 0; s < 4; ++s) {
            #pragma unroll
            for (int c = 0; c < 8; ++c) {
                half8_t bf = *(const half8_t*)(wbase + c * (16 * 136) + s * 32);
                acc[c] = __builtin_amdgcn_mfma_f32_16x16x32_f16(af[s], bf, acc[c], 0, 0, 0);
            }
        }

        // Epilogue. D layout: col = c*16 + l16, row(node) = base + q*4 + r.
        const bool full = (base + 16 <= N);
        #pragma unroll
        for (int c = 0; c < 8; ++c) {
            #pragma unroll
            for (int r = 0; r < 4; ++r) {
                int rr = base + q * 4 + r;
                if (full || rr < N)
                    Wh16[(size_t)rr * 128 + (c * 16 + l16)] = __float2half(acc[c][r]);
            }
        }
        // reduce e1/e2 partials over the 4 q-chunks (lanes same l16)
        pe1 += __shfl_xor(pe1, 16); pe1 += __shfl_xor(pe1, 32);
        pe2 += __shfl_xor(pe2, 16); pe2 += __shfl_xor(pe2, 32);
        if (lane < 16) {
            int rr = base + lane;
            if (rr < N) { e1[rr] = pe1 + abv; e2[rr] = pe2; }
        }
    }
}

// k2: 4 nodes per wave (one per 16-lane quarter). Each lane owns 2
// neighbors (int2 ctx load) and 8 output dims (half8 = 16 B row chunk).
// Quarter-local softmax via width-16 shuffles. All 32 (weight, offset)
// pairs are materialized in registers FIRST (static indexing), then a
// fully-unrolled gather loop keeps up to 32 16 B loads in flight per lane
// — occupancy is grid-limited (~4.9 blocks/CU), so the VGPR spend is free.
__global__ __launch_bounds__(256, 4) void gat_gather4(
    const int* __restrict__ ctx, const float* __restrict__ e1,
    const float* __restrict__ e2, const __half* __restrict__ Wh16,
    float* __restrict__ out, int N) {
    const int t = threadIdx.x;
    const int wave = t >> 6, lane = t & 63, qid = lane >> 4, l = lane & 15;
    const int widx = blockIdx.x * 4 + wave;
    if (widx * 4 >= N) return;  // wave-uniform exit
    const int n = widx * 4 + qid;
    const bool okn = (n < N);
    const int nn = okn ? n : (N - 1);

    int2 ij = ((const int2*)(ctx + (size_t)nn * 32))[l];  // neighbors 2l,2l+1
    const bool v0 = (ij.x >= 0), v1 = (ij.y >= 0);
    const int j0 = v0 ? ij.x : 0, j1 = v1 ? ij.y : 0;
    const float eb = e1[nn];  // includes a_b
    float lg0 = eb + e2[j0], lg1 = eb + e2[j1];
    lg0 = fmaxf(lg0, GAT_ALPHA * lg0);  // leaky_relu (alpha<1)
    lg1 = fmaxf(lg1, GAT_ALPHA * lg1);
    lg0 = v0 ? lg0 : GAT_NEG_INF;
    lg1 = v1 ? lg1 : GAT_NEG_INF;
    float m = fmaxf(lg0, lg1);
    #pragma unroll
    for (int s = 8; s; s >>= 1) m = fmaxf(m, __shfl_xor(m, s, 16));
    float p0 = v0 ? __expf(lg0 - m) : 0.f;
    float p1 = v1 ? __expf(lg1 - m) : 0.f;
    float ss = p0 + p1;
    #pragma unroll
    for (int s = 8; s; s >>= 1) ss += __shfl_xor(ss, s, 16);
    const float inv = (ss > 0.f) ? __frcp_rn(ss) : 0.f;
    p0 *= inv; p1 *= inv;

    const int o0 = j0 << 8, o1 = j1 << 8;  // byte offset of 256 B rows

    // Phase 1: distribute all 32 (weight, offset) pairs (fully unrolled →
    // static indexing → registers, not scratch)
    float w[32]; int off[32];
    #pragma unroll
    for (int cc = 0; cc < 32; ++cc) {
        const int src = cc >> 1;
        w[cc]   = __shfl((cc & 1) ? p1 : p0, src, 16);
        off[cc] = __shfl((cc & 1) ? o1 : o0, src, 16);
    }

    // Phase 2: gather-accumulate, fully unrolled (max MLP)
    float a0 = 0.f, a1 = 0.f, a2 = 0.f, a3 = 0.f;
    float a4 = 0.f, a5 = 0.f, a6 = 0.f, a7 = 0.f;
    const char* wb = (const char*)Wh16 + (size_t)(l * 16);
    #pragma unroll
    for (int cc = 0; cc < 32; ++cc) {
        half8_t hv = *(const half8_t*)(wb + off[cc]);  // 16 B, quarter = 256 B row
        const float wc = w[cc];
        a0 = fmaf(wc, (float)hv[0], a0); a1 = fmaf(wc, (float)hv[1], a1);
        a2 = fmaf(wc, (float)hv[2], a2); a3 = fmaf(wc, (float)hv[3], a3);
        a4 = fmaf(wc, (float)hv[4], a4); a5 = fmaf(wc, (float)hv[5], a5);
        a6 = fmaf(wc, (float)hv[6], a6); a7 = fmaf(wc, (float)hv[7], a7);
    }
    if (okn) {
        float4* orow = (float4*)(out + (size_t)n * 128);
        float4 u; u.x = a0; u.y = a1; u.z = a2; u.w = a3;
        float4 v; v.x = a4; v.y = a5; v.z = a6; v.w = a7;
        orow[2 * l] = u;
        orow[2 * l + 1] = v;
    }
}

extern "C" void kernel_launch(void* const* d_in, const int* in_sizes, int n_in,
                              void* d_out, int out_size, void* d_ws, size_t ws_size,
                              hipStream_t stream) {
    const float* h   = (const float*)d_in[0];
    const int*   ctx = (const int*)d_in[1];
    const float* Wi  = (const float*)d_in[2];
    const float* Wj  = (const float*)d_in[3];
    const float* aw  = (const float*)d_in[4];
    const float* ab  = (const float*)d_in[5];
    float* out = (float*)d_out;
    const int N = in_sizes[0] / 128;

    // workspace: e1[N] | e2[N] | Wh16[N*128] fp16
    float* e1 = (float*)d_ws;
    float* e2 = e1 + N;
    __half* Wh16 = (__half*)(e2 + N);

    const int ntiles = (N + 15) >> 4;       // 16-node MFMA tiles
    const int g1 = (ntiles + 3) / 4;        // 4 waves/block, 1 tile/wave
    const int nquad = (N + 3) / 4;          // 4 nodes/wave
    const int g2 = (nquad + 3) / 4;

    gat_transform_mfma<<<g1, 256, 0, stream>>>(h, Wi, Wj, aw, ab, Wh16, e1, e2, N);
    gat_gather4<<<g2, 256, 0, stream>>>(ctx, e1, e2, Wh16, out, N);
}

// Round 2
// 102.315 us; speedup vs baseline: 1.4294x; 1.4294x over previous
//
#include <hip/hip_runtime.h>
#include <hip/hip_fp16.h>

#define GAT_ALPHA 0.2f
#define GAT_NEG_INF -9.0e15f

typedef _Float16 half8_t __attribute__((ext_vector_type(8)));
typedef float f32x4 __attribute__((ext_vector_type(4)));

// k1: MFMA f16 GEMM. Wh16 = fp16(h @ W_j); e2 = Wh@a_j (fp32 acc);
// e1 = h@vi + ab (fp32, vi = W_i@a_i computed in the prologue into LDS).
// One wave = one 16-node tile. A-frag from global fp32 (cvt in-reg);
// B-frag: W_j^T fp16 in LDS, row stride 136 halves.
// (Round-0 version, reverted: the vjr-register variant spilled/regressed.)
__global__ __launch_bounds__(256) void gat_transform_mfma(
    const float* __restrict__ h, const float* __restrict__ Wi,
    const float* __restrict__ Wj, const float* __restrict__ aw,
    const float* __restrict__ ab,
    __half* __restrict__ Wh16, float* __restrict__ e1, float* __restrict__ e2,
    int N) {
    __shared__ _Float16 sWt[128 * 136];  // W_j^T, padded: 34816 B
    __shared__ float svi[128];           // vi = W_i @ a_i
    const int t = threadIdx.x;

    // prologue 1: vi (threads 0..127; ~64KB of W_i from L2, broadcast a_w)
    if (t < 128) {
        const float4* wrow = (const float4*)(Wi + (size_t)t * 128);
        const float4* a4 = (const float4*)aw;  // a_i = aw[0:128]
        float s = 0.f;
        #pragma unroll
        for (int i = 0; i < 32; ++i) {
            float4 w = wrow[i], a = a4[i];
            s = fmaf(w.x, a.x, s); s = fmaf(w.y, a.y, s);
            s = fmaf(w.z, a.z, s); s = fmaf(w.w, a.w, s);
        }
        svi[t] = s;
    }
    // prologue 2: W_j^T into LDS as fp16
    for (int i = t; i < 128 * 128; i += 256) {
        int k = i >> 7, n = i & 127;          // W_j[k][n] row-major read
        sWt[n * 136 + k] = (_Float16)Wj[i];
    }
    __syncthreads();

    const int wave = t >> 6, lane = t & 63, q = lane >> 4, l16 = lane & 15;
    const float abv = ab[0];

    // vi chunk this lane consumes for e1: vi[s*32 + q*8 + j]
    float vir[4][8];
    #pragma unroll
    for (int s = 0; s < 4; ++s) {
        float4 u0 = *(const float4*)(svi + s * 32 + q * 8);
        float4 u1 = *(const float4*)(svi + s * 32 + q * 8 + 4);
        vir[s][0] = u0.x; vir[s][1] = u0.y; vir[s][2] = u0.z; vir[s][3] = u0.w;
        vir[s][4] = u1.x; vir[s][5] = u1.y; vir[s][6] = u1.z; vir[s][7] = u1.w;
    }
    // a_j value for this lane's output column in each of the 8 col-tiles
    float ajr[8];
    #pragma unroll
    for (int c = 0; c < 8; ++c) ajr[c] = aw[128 + c * 16 + l16];

    const int ntiles = (N + 15) >> 4;
    for (int tile = blockIdx.x * 4 + wave; tile < ntiles; tile += gridDim.x * 4) {
        const int base = tile << 4;
        int row = base + l16; if (row >= N) row = N - 1;  // clamp tail
        const float* hp = h + (size_t)row * 128 + q * 8;

        half8_t af[4];
        float pe1 = 0.f;  // fp32-exact partial of h[row]·vi
        #pragma unroll
        for (int s = 0; s < 4; ++s) {
            float4 f0 = *(const float4*)(hp + s * 32);
            float4 f1 = *(const float4*)(hp + s * 32 + 4);
            pe1 = fmaf(f0.x, vir[s][0], pe1); pe1 = fmaf(f0.y, vir[s][1], pe1);
            pe1 = fmaf(f0.z, vir[s][2], pe1); pe1 = fmaf(f0.w, vir[s][3], pe1);
            pe1 = fmaf(f1.x, vir[s][4], pe1); pe1 = fmaf(f1.y, vir[s][5], pe1);
            pe1 = fmaf(f1.z, vir[s][6], pe1); pe1 = fmaf(f1.w, vir[s][7], pe1);
            half8_t a;
            a[0] = (_Float16)f0.x; a[1] = (_Float16)f0.y;
            a[2] = (_Float16)f0.z; a[3] = (_Float16)f0.w;
            a[4] = (_Float16)f1.x; a[5] = (_Float16)f1.y;
            a[6] = (_Float16)f1.z; a[7] = (_Float16)f1.w;
            af[s] = a;
        }

        f32x4 acc[8];
        #pragma unroll
        for (int c = 0; c < 8; ++c) { f32x4 z = {0.f, 0.f, 0.f, 0.f}; acc[c] = z; }

        const _Float16* wbase = sWt + l16 * 136 + q * 8;
        #pragma unroll
        for (int s = 0; s < 4; ++s) {
            #pragma unroll
            for (int c = 0; c < 8; ++c) {
                half8_t bf = *(const half8_t*)(wbase + c * (16 * 136) + s * 32);
                acc[c] = __builtin_amdgcn_mfma_f32_16x16x32_f16(af[s], bf, acc[c], 0, 0, 0);
            }
        }

        // Epilogue. D layout: col = c*16 + l16, row(node) = base + q*4 + r.
        const bool full = (base + 16 <= N);
        float pe2[4] = {0.f, 0.f, 0.f, 0.f};
        #pragma unroll
        for (int c = 0; c < 8; ++c) {
            #pragma unroll
            for (int r = 0; r < 4; ++r) {
                float v = acc[c][r];
                pe2[r] = fmaf(v, ajr[c], pe2[r]);
                int rr = base + q * 4 + r;
                if (full || rr < N)
                    Wh16[(size_t)rr * 128 + (c * 16 + l16)] = __float2half(v);
            }
        }
        #pragma unroll
        for (int r = 0; r < 4; ++r) {  // reduce over the 16 cols held in-quad
            pe2[r] += __shfl_xor(pe2[r], 1);
            pe2[r] += __shfl_xor(pe2[r], 2);
            pe2[r] += __shfl_xor(pe2[r], 4);
            pe2[r] += __shfl_xor(pe2[r], 8);
        }
        if (l16 == 0) {
            #pragma unroll
            for (int r = 0; r < 4; ++r) {
                int rr = base + q * 4 + r;
                if (rr < N) e2[rr] = pe2[r];
            }
        }
        pe1 += __shfl_xor(pe1, 16);  // reduce over q (k-chunks)
        pe1 += __shfl_xor(pe1, 32);
        if (lane < 16) {
            int rr = base + lane;
            if (rr < N) e1[rr] = pe1 + abv;
        }
    }
}

// k2: ONE node per wave (4 nodes/block). 4x the wave count of the old
// 4-nodes-per-wave version -> 8 resident waves/SIMD (latency hiding via
// TLP, not per-wave register arrays, which spilled in round 1).
// Lanes 0..31 own one neighbor each (lanes 32..63 duplicate) -> width-32
// shuffle softmax. Gather: quarter q handles neighbors 8q..8q+7; lane
// covers a 16B dim-chunk of the 256B row; cross-quarter shfl_xor reduce.
__global__ __launch_bounds__(256, 8) void gat_gather1(
    const int* __restrict__ ctx, const float* __restrict__ e1,
    const float* __restrict__ e2, const __half* __restrict__ Wh16,
    float* __restrict__ out, int N) {
    const int t = threadIdx.x;
    const int wave = t >> 6, lane = t & 63;
    const int qq = lane >> 4, ll = lane & 15;
    const int n = blockIdx.x * 4 + wave;
    if (n >= N) return;  // wave-uniform exit

    // neighbor c = lane&31 (lanes 32..63 mirror lanes 0..31)
    const int c32 = lane & 31;
    const int j = ctx[(size_t)n * 32 + c32];
    const bool v = (j >= 0);
    const int jj = v ? j : 0;
    const float eb = e1[n];  // includes a_b
    float lg = eb + e2[jj];
    lg = fmaxf(lg, GAT_ALPHA * lg);  // leaky_relu (alpha<1)
    lg = v ? lg : GAT_NEG_INF;
    float m = lg;
    #pragma unroll
    for (int s = 16; s; s >>= 1) m = fmaxf(m, __shfl_xor(m, s, 32));
    float p = v ? __expf(lg - m) : 0.f;
    float ss = p;
    #pragma unroll
    for (int s = 16; s; s >>= 1) ss += __shfl_xor(ss, s, 32);
    const float inv = (ss > 0.f) ? __frcp_rn(ss) : 0.f;
    p *= inv;
    const int o = jj << 8;  // byte offset of the 256B Wh16 row

    float a0 = 0.f, a1 = 0.f, a2 = 0.f, a3 = 0.f;
    float a4 = 0.f, a5 = 0.f, a6 = 0.f, a7 = 0.f;
    const char* wb = (const char*)Wh16 + (size_t)(ll * 16);
    #pragma unroll
    for (int k = 0; k < 8; ++k) {
        const int src = qq * 8 + k;        // this quarter's k-th neighbor
        const float w = __shfl(p, src, 32);
        const int  off = __shfl(o, src, 32);
        half8_t hv = *(const half8_t*)(wb + off);  // 16B; quarter = 256B row
        a0 = fmaf(w, (float)hv[0], a0); a1 = fmaf(w, (float)hv[1], a1);
        a2 = fmaf(w, (float)hv[2], a2); a3 = fmaf(w, (float)hv[3], a3);
        a4 = fmaf(w, (float)hv[4], a4); a5 = fmaf(w, (float)hv[5], a5);
        a6 = fmaf(w, (float)hv[6], a6); a7 = fmaf(w, (float)hv[7], a7);
    }
    // cross-quarter reduction: quarters hold disjoint neighbor subsets of
    // the SAME dim-chunk layout -> butterfly over lane bits 4,5
    a0 += __shfl_xor(a0, 16); a1 += __shfl_xor(a1, 16);
    a2 += __shfl_xor(a2, 16); a3 += __shfl_xor(a3, 16);
    a4 += __shfl_xor(a4, 16); a5 += __shfl_xor(a5, 16);
    a6 += __shfl_xor(a6, 16); a7 += __shfl_xor(a7, 16);
    a0 += __shfl_xor(a0, 32); a1 += __shfl_xor(a1, 32);
    a2 += __shfl_xor(a2, 32); a3 += __shfl_xor(a3, 32);
    a4 += __shfl_xor(a4, 32); a5 += __shfl_xor(a5, 32);
    a6 += __shfl_xor(a6, 32); a7 += __shfl_xor(a7, 32);

    if (lane < 16) {  // 16 lanes x 32B contiguous = 512B row
        float4* orow = (float4*)(out + (size_t)n * 128);
        float4 u; u.x = a0; u.y = a1; u.z = a2; u.w = a3;
        float4 w2; w2.x = a4; w2.y = a5; w2.z = a6; w2.w = a7;
        orow[2 * ll] = u;
        orow[2 * ll + 1] = w2;
    }
}

extern "C" void kernel_launch(void* const* d_in, const int* in_sizes, int n_in,
                              void* d_out, int out_size, void* d_ws, size_t ws_size,
                              hipStream_t stream) {
    const float* h   = (const float*)d_in[0];
    const int*   ctx = (const int*)d_in[1];
    const float* Wi  = (const float*)d_in[2];
    const float* Wj  = (const float*)d_in[3];
    const float* aw  = (const float*)d_in[4];
    const float* ab  = (const float*)d_in[5];
    float* out = (float*)d_out;
    const int N = in_sizes[0] / 128;

    // workspace: e1[N] | e2[N] | Wh16[N*128] fp16
    float* e1 = (float*)d_ws;
    float* e2 = e1 + N;
    __half* Wh16 = (__half*)(e2 + N);

    const int ntiles = (N + 15) >> 4;       // 16-node MFMA tiles
    const int g1 = (ntiles + 3) / 4;        // 4 waves/block, 1 tile/wave
    const int g2 = (N + 3) / 4;             // 1 node/wave, 4 waves/block

    gat_transform_mfma<<<g1, 256, 0, stream>>>(h, Wi, Wj, aw, ab, Wh16, e1, e2, N);
    gat_gather1<<<g2, 256, 0, stream>>>(ctx, e1, e2, Wh16, out, N);
}

// Round 3
// 102.305 us; speedup vs baseline: 1.4295x; 1.0001x over previous
//
#include <hip/hip_runtime.h>
#include <hip/hip_fp16.h>

#define GAT_ALPHA 0.2f
#define GAT_NEG_INF -9.0e15f

typedef _Float16 half8_t __attribute__((ext_vector_type(8)));
typedef float f32x4 __attribute__((ext_vector_type(4)));

// k1: MFMA f16 GEMM. Wh16 = fp16(h @ W_j); e2 = Wh@a_j (fp32 acc);
// e1 = h@vi + ab (fp32, vi = W_i@a_i computed in the prologue into LDS).
// One wave = one 16-node tile. (Round-0 version, known-good ~11 us.)
__global__ __launch_bounds__(256) void gat_transform_mfma(
    const float* __restrict__ h, const float* __restrict__ Wi,
    const float* __restrict__ Wj, const float* __restrict__ aw,
    const float* __restrict__ ab,
    __half* __restrict__ Wh16, float* __restrict__ e1, float* __restrict__ e2,
    int N) {
    __shared__ _Float16 sWt[128 * 136];  // W_j^T, padded: 34816 B
    __shared__ float svi[128];           // vi = W_i @ a_i
    const int t = threadIdx.x;

    // prologue 1: vi (threads 0..127; ~64KB of W_i from L2, broadcast a_w)
    if (t < 128) {
        const float4* wrow = (const float4*)(Wi + (size_t)t * 128);
        const float4* a4 = (const float4*)aw;  // a_i = aw[0:128]
        float s = 0.f;
        #pragma unroll
        for (int i = 0; i < 32; ++i) {
            float4 w = wrow[i], a = a4[i];
            s = fmaf(w.x, a.x, s); s = fmaf(w.y, a.y, s);
            s = fmaf(w.z, a.z, s); s = fmaf(w.w, a.w, s);
        }
        svi[t] = s;
    }
    // prologue 2: W_j^T into LDS as fp16
    for (int i = t; i < 128 * 128; i += 256) {
        int k = i >> 7, n = i & 127;          // W_j[k][n] row-major read
        sWt[n * 136 + k] = (_Float16)Wj[i];
    }
    __syncthreads();

    const int wave = t >> 6, lane = t & 63, q = lane >> 4, l16 = lane & 15;
    const float abv = ab[0];

    // vi chunk this lane consumes for e1: vi[s*32 + q*8 + j]
    float vir[4][8];
    #pragma unroll
    for (int s = 0; s < 4; ++s) {
        float4 u0 = *(const float4*)(svi + s * 32 + q * 8);
        float4 u1 = *(const float4*)(svi + s * 32 + q * 8 + 4);
        vir[s][0] = u0.x; vir[s][1] = u0.y; vir[s][2] = u0.z; vir[s][3] = u0.w;
        vir[s][4] = u1.x; vir[s][5] = u1.y; vir[s][6] = u1.z; vir[s][7] = u1.w;
    }
    // a_j value for this lane's output column in each of the 8 col-tiles
    float ajr[8];
    #pragma unroll
    for (int c = 0; c < 8; ++c) ajr[c] = aw[128 + c * 16 + l16];

    const int ntiles = (N + 15) >> 4;
    for (int tile = blockIdx.x * 4 + wave; tile < ntiles; tile += gridDim.x * 4) {
        const int base = tile << 4;
        int row = base + l16; if (row >= N) row = N - 1;  // clamp tail
        const float* hp = h + (size_t)row * 128 + q * 8;

        half8_t af[4];
        float pe1 = 0.f;  // fp32-exact partial of h[row]·vi
        #pragma unroll
        for (int s = 0; s < 4; ++s) {
            float4 f0 = *(const float4*)(hp + s * 32);
            float4 f1 = *(const float4*)(hp + s * 32 + 4);
            pe1 = fmaf(f0.x, vir[s][0], pe1); pe1 = fmaf(f0.y, vir[s][1], pe1);
            pe1 = fmaf(f0.z, vir[s][2], pe1); pe1 = fmaf(f0.w, vir[s][3], pe1);
            pe1 = fmaf(f1.x, vir[s][4], pe1); pe1 = fmaf(f1.y, vir[s][5], pe1);
            pe1 = fmaf(f1.z, vir[s][6], pe1); pe1 = fmaf(f1.w, vir[s][7], pe1);
            half8_t a;
            a[0] = (_Float16)f0.x; a[1] = (_Float16)f0.y;
            a[2] = (_Float16)f0.z; a[3] = (_Float16)f0.w;
            a[4] = (_Float16)f1.x; a[5] = (_Float16)f1.y;
            a[6] = (_Float16)f1.z; a[7] = (_Float16)f1.w;
            af[s] = a;
        }

        f32x4 acc[8];
        #pragma unroll
        for (int c = 0; c < 8; ++c) { f32x4 z = {0.f, 0.f, 0.f, 0.f}; acc[c] = z; }

        const _Float16* wbase = sWt + l16 * 136 + q * 8;
        #pragma unroll
        for (int s = 0; s < 4; ++s) {
            #pragma unroll
            for (int c = 0; c < 8; ++c) {
                half8_t bf = *(const half8_t*)(wbase + c * (16 * 136) + s * 32);
                acc[c] = __builtin_amdgcn_mfma_f32_16x16x32_f16(af[s], bf, acc[c], 0, 0, 0);
            }
        }

        // Epilogue. D layout: col = c*16 + l16, row(node) = base + q*4 + r.
        const bool full = (base + 16 <= N);
        float pe2[4] = {0.f, 0.f, 0.f, 0.f};
        #pragma unroll
        for (int c = 0; c < 8; ++c) {
            #pragma unroll
            for (int r = 0; r < 4; ++r) {
                float v = acc[c][r];
                pe2[r] = fmaf(v, ajr[c], pe2[r]);
                int rr = base + q * 4 + r;
                if (full || rr < N)
                    Wh16[(size_t)rr * 128 + (c * 16 + l16)] = __float2half(v);
            }
        }
        #pragma unroll
        for (int r = 0; r < 4; ++r) {  // reduce over the 16 cols held in-quad
            pe2[r] += __shfl_xor(pe2[r], 1);
            pe2[r] += __shfl_xor(pe2[r], 2);
            pe2[r] += __shfl_xor(pe2[r], 4);
            pe2[r] += __shfl_xor(pe2[r], 8);
        }
        if (l16 == 0) {
            #pragma unroll
            for (int r = 0; r < 4; ++r) {
                int rr = base + q * 4 + r;
                if (rr < N) e2[rr] = pe2[r];
            }
        }
        pe1 += __shfl_xor(pe1, 16);  // reduce over q (k-chunks)
        pe1 += __shfl_xor(pe1, 32);
        if (lane < 16) {
            int rr = base + lane;
            if (rr < N) e1[rr] = pe1 + abv;
        }
    }
}

// k2: 1 node/wave, EXPLICIT issue order: ctx -> e2 gather -> ALL 8 row
// gathers issued into named registers -> softmax runs with 9 loads in
// flight -> weights -> fma. Discriminating experiment: if k2 was
// scheduling/latency-bound this drops ~45->~30 us; if the chip's random-
// gather miss-concurrency cap binds, it stays flat (-> roofline).
// Named scalars only (rule #20); (256,6) = 85-VGPR cap, no spill risk.
__global__ __launch_bounds__(256, 6) void gat_gather1(
    const int* __restrict__ ctx, const float* __restrict__ e1,
    const float* __restrict__ e2, const __half* __restrict__ Wh16,
    float* __restrict__ out, int N) {
    const int t = threadIdx.x;
    const int wave = t >> 6, lane = t & 63;
    const int qq = lane >> 4, ll = lane & 15;
    const int n = blockIdx.x * 4 + wave;
    if (n >= N) return;  // wave-uniform exit

    // (1) root dependency: neighbor index (lane&31; upper half mirrors)
    const int c32 = lane & 31;
    const int j = ctx[(size_t)n * 32 + c32];
    const bool v = (j >= 0);
    const int jj = v ? j : 0;
    const float eb = e1[n];          // wave-uniform scalar load, early

    // (2) issue the e2 gather immediately (it gates the softmax chain)
    const float e2v = e2[jj];

    // (3) distribute this quarter's 8 row offsets and issue ALL 8 gathers
    //     BEFORE softmax consumes e2v — 8 rows in flight under the chain.
    const int o = jj << 8;           // byte offset of the 256B Wh16 row
    const int qb = qq * 8;
    const char* wb = (const char*)Wh16 + (size_t)(ll * 16);
    const int off0 = __shfl(o, qb + 0, 32);
    const int off1 = __shfl(o, qb + 1, 32);
    const int off2 = __shfl(o, qb + 2, 32);
    const int off3 = __shfl(o, qb + 3, 32);
    const int off4 = __shfl(o, qb + 4, 32);
    const int off5 = __shfl(o, qb + 5, 32);
    const int off6 = __shfl(o, qb + 6, 32);
    const int off7 = __shfl(o, qb + 7, 32);
    half8_t hv0 = *(const half8_t*)(wb + off0);
    half8_t hv1 = *(const half8_t*)(wb + off1);
    half8_t hv2 = *(const half8_t*)(wb + off2);
    half8_t hv3 = *(const half8_t*)(wb + off3);
    half8_t hv4 = *(const half8_t*)(wb + off4);
    half8_t hv5 = *(const half8_t*)(wb + off5);
    half8_t hv6 = *(const half8_t*)(wb + off6);
    half8_t hv7 = *(const half8_t*)(wb + off7);

    // (4) softmax over the 32 neighbors (width-32 shuffles)
    float lg = eb + e2v;
    lg = fmaxf(lg, GAT_ALPHA * lg);  // leaky_relu (alpha<1)
    lg = v ? lg : GAT_NEG_INF;
    float m = lg;
    #pragma unroll
    for (int s = 16; s; s >>= 1) m = fmaxf(m, __shfl_xor(m, s, 32));
    float p = v ? __expf(lg - m) : 0.f;
    float ss = p;
    #pragma unroll
    for (int s = 16; s; s >>= 1) ss += __shfl_xor(ss, s, 32);
    const float inv = (ss > 0.f) ? __frcp_rn(ss) : 0.f;
    p *= inv;

    // (5) weights for this quarter's 8 rows
    const float w0 = __shfl(p, qb + 0, 32);
    const float w1 = __shfl(p, qb + 1, 32);
    const float w2 = __shfl(p, qb + 2, 32);
    const float w3 = __shfl(p, qb + 3, 32);
    const float w4 = __shfl(p, qb + 4, 32);
    const float w5 = __shfl(p, qb + 5, 32);
    const float w6 = __shfl(p, qb + 6, 32);
    const float w7 = __shfl(p, qb + 7, 32);

    // (6) weighted accumulate (compiler forms v_fma_mix from f16 casts)
    float a0 = 0.f, a1 = 0.f, a2 = 0.f, a3 = 0.f;
    float a4 = 0.f, a5 = 0.f, a6 = 0.f, a7 = 0.f;
#define GAT_ACC(HV, W)                                                   \
    a0 = fmaf(W, (float)HV[0], a0); a1 = fmaf(W, (float)HV[1], a1);      \
    a2 = fmaf(W, (float)HV[2], a2); a3 = fmaf(W, (float)HV[3], a3);      \
    a4 = fmaf(W, (float)HV[4], a4); a5 = fmaf(W, (float)HV[5], a5);      \
    a6 = fmaf(W, (float)HV[6], a6); a7 = fmaf(W, (float)HV[7], a7);
    GAT_ACC(hv0, w0) GAT_ACC(hv1, w1) GAT_ACC(hv2, w2) GAT_ACC(hv3, w3)
    GAT_ACC(hv4, w4) GAT_ACC(hv5, w5) GAT_ACC(hv6, w6) GAT_ACC(hv7, w7)
#undef GAT_ACC

    // (7) cross-quarter reduction (quarters hold disjoint neighbor subsets
    //     of the SAME dim-chunk layout) -> butterfly over lane bits 4,5
    a0 += __shfl_xor(a0, 16); a1 += __shfl_xor(a1, 16);
    a2 += __shfl_xor(a2, 16); a3 += __shfl_xor(a3, 16);
    a4 += __shfl_xor(a4, 16); a5 += __shfl_xor(a5, 16);
    a6 += __shfl_xor(a6, 16); a7 += __shfl_xor(a7, 16);
    a0 += __shfl_xor(a0, 32); a1 += __shfl_xor(a1, 32);
    a2 += __shfl_xor(a2, 32); a3 += __shfl_xor(a3, 32);
    a4 += __shfl_xor(a4, 32); a5 += __shfl_xor(a5, 32);
    a6 += __shfl_xor(a6, 32); a7 += __shfl_xor(a7, 32);

    if (lane < 16) {  // 16 lanes x 32B contiguous = 512B row
        float4* orow = (float4*)(out + (size_t)n * 128);
        float4 u; u.x = a0; u.y = a1; u.z = a2; u.w = a3;
        float4 w2v; w2v.x = a4; w2v.y = a5; w2v.z = a6; w2v.w = a7;
        orow[2 * ll] = u;
        orow[2 * ll + 1] = w2v;
    }
}

extern "C" void kernel_launch(void* const* d_in, const int* in_sizes, int n_in,
                              void* d_out, int out_size, void* d_ws, size_t ws_size,
                              hipStream_t stream) {
    const float* h   = (const float*)d_in[0];
    const int*   ctx = (const int*)d_in[1];
    const float* Wi  = (const float*)d_in[2];
    const float* Wj  = (const float*)d_in[3];
    const float* aw  = (const float*)d_in[4];
    const float* ab  = (const float*)d_in[5];
    float* out = (float*)d_out;
    const int N = in_sizes[0] / 128;

    // workspace: e1[N] | e2[N] | Wh16[N*128] fp16
    float* e1 = (float*)d_ws;
    float* e2 = e1 + N;
    __half* Wh16 = (__half*)(e2 + N);

    const int ntiles = (N + 15) >> 4;       // 16-node MFMA tiles
    const int g1 = (ntiles + 3) / 4;        // 4 waves/block, 1 tile/wave
    const int g2 = (N + 3) / 4;             // 1 node/wave, 4 waves/block

    gat_transform_mfma<<<g1, 256, 0, stream>>>(h, Wi, Wj, aw, ab, Wh16, e1, e2, N);
    gat_gather1<<<g2, 256, 0, stream>>>(ctx, e1, e2, Wh16, out, N);
}